// Round 1
// baseline (1532.568 us; speedup 1.0000x reference)
//
#include <hip/hip_runtime.h>

#define NN 100000
#define NE 1600000
#define HD 128
#define NL 3
#define NG 256

typedef __attribute__((ext_vector_type(8))) short short8;
typedef __attribute__((ext_vector_type(4))) float floatx4;

static __device__ __forceinline__ unsigned short f2bf(float f) {
    unsigned int u = __float_as_uint(f);
    u += 0x7fffu + ((u >> 16) & 1u);
    return (unsigned short)(u >> 16);
}
static __device__ __forceinline__ float bf2f(unsigned short h) {
    return __uint_as_float(((unsigned int)h) << 16);
}
static __device__ __forceinline__ float angle3(float ax, float ay, float az,
                                               float bx, float by, float bz) {
    float cx = ay*bz - az*by;
    float cy = az*bx - ax*bz;
    float cz = ax*by - ay*bx;
    float cn = sqrtf(cx*cx + cy*cy + cz*cz);
    float d  = ax*bx + ay*by + az*bz;
    return atan2f(cn, d);
}

// ---------------- preprocessing ----------------

__global__ void k_normal(const float* __restrict__ pos, float* __restrict__ nrm, int n) {
    int i = blockIdx.x * blockDim.x + threadIdx.x;
    if (i >= n) return;
    float x = pos[3*i], y = pos[3*i+1], z = pos[3*i+2];
    float inv = 1.0f / (sqrtf(x*x + y*y + z*z) + 1e-12f);
    nrm[3*i] = x*inv; nrm[3*i+1] = y*inv; nrm[3*i+2] = z*inv;
}

__global__ void k_hist(const int* __restrict__ ei, int* __restrict__ deg, int e) {
    int i = blockIdx.x * blockDim.x + threadIdx.x;
    if (i >= e) return;
    atomicAdd(&deg[ei[NE + i]], 1);
}

__global__ void k_scan1(const int* __restrict__ deg, int* __restrict__ starts,
                        int* __restrict__ bsum, int n) {
    __shared__ int s[1024];
    int i = blockIdx.x * 1024 + threadIdx.x;
    int v = (i < NN) ? deg[i] : 0;
    s[threadIdx.x] = v;
    for (int off = 1; off < 1024; off <<= 1) {
        __syncthreads();
        int t = (threadIdx.x >= off) ? s[threadIdx.x - off] : 0;
        __syncthreads();
        s[threadIdx.x] += t;
    }
    if (i < n) starts[i] = s[threadIdx.x] - v;  // exclusive
    if (threadIdx.x == 1023) bsum[blockIdx.x] = s[1023];
}

__global__ void k_scan2(int* __restrict__ bsum, int nb) {
    if (threadIdx.x == 0 && blockIdx.x == 0) {
        int acc = 0;
        for (int i = 0; i < nb; i++) { int v = bsum[i]; bsum[i] = acc; acc += v; }
    }
}

__global__ void k_scan3(int* __restrict__ starts, const int* __restrict__ bsum, int n) {
    int i = blockIdx.x * blockDim.x + threadIdx.x;
    if (i < n) starts[i] += bsum[i >> 10];
}

// compute ppf per edge and scatter into dst-sorted order (counting sort)
__global__ void k_ppf_scatter(const int* __restrict__ ei, const float* __restrict__ pos,
                              const float* __restrict__ nrm, int* __restrict__ cursor,
                              int* __restrict__ ssrc, float4* __restrict__ sppf, int e) {
    int i = blockIdx.x * blockDim.x + threadIdx.x;
    if (i >= e) return;
    int s = ei[i];        // src (j)
    int d = ei[NE + i];   // dst (i)
    float px = pos[3*s] - pos[3*d];
    float py = pos[3*s+1] - pos[3*d+1];
    float pz = pos[3*s+2] - pos[3*d+2];
    float nix = nrm[3*d], niy = nrm[3*d+1], niz = nrm[3*d+2];
    float njx = nrm[3*s], njy = nrm[3*s+1], njz = nrm[3*s+2];
    float f0 = sqrtf(px*px + py*py + pz*pz);
    float f1 = angle3(nix, niy, niz, px, py, pz);
    float f2 = angle3(njx, njy, njz, px, py, pz);
    float f3 = angle3(nix, niy, niz, njx, njy, njz);
    int p = atomicAdd(&cursor[d], 1);
    ssrc[p] = s;
    sppf[p] = make_float4(f0, f1, f2, f3);
}

// ---------------- node_lin first layer: u = relu(x@W1 + b1), K=16 ----------------

__global__ void k_node_lin1(const float* __restrict__ x, const float* __restrict__ W1,
                            const float* __restrict__ b1, unsigned short* __restrict__ u, int n) {
    __shared__ float sW[16 * HD];
    __shared__ float sb[HD];
    __shared__ float sx[16 * 16];
    int tid = threadIdx.x;
    for (int idx = tid; idx < 16 * HD; idx += 256) sW[idx] = W1[idx];
    if (tid < HD) sb[tid] = b1[tid];
    int r0 = blockIdx.x * 16;
    for (int idx = tid; idx < 16 * 16; idx += 256) {
        int r = r0 + (idx >> 4);
        sx[idx] = (r < n) ? x[r * 16 + (idx & 15)] : 0.0f;
    }
    __syncthreads();
    int col = tid & 127;
    int rsub = tid >> 7;
    float wcol[16];
#pragma unroll
    for (int k = 0; k < 16; k++) wcol[k] = sW[k * HD + col];
    float bb = sb[col];
    for (int rr = rsub; rr < 16; rr += 2) {
        int r = r0 + rr;
        if (r >= n) break;
        float acc = bb;
#pragma unroll
        for (int k = 0; k < 16; k++) acc = fmaf(sx[rr * 16 + k], wcol[k], acc);
        u[r * HD + col] = f2bf(fmaxf(acc, 0.0f));
    }
}

// ---------------- main MFMA GEMM: [n,128] bf16 @ [128,NC] f32 -> [n,NC] bf16 ----------------
// EPI: 0 = none, 1 = +bias, 2 = +deg*b2, 3 = +bias,relu

template <int NC, int EPI>
__global__ __launch_bounds__(256, 2) void k_gemm128(
    const unsigned short* __restrict__ A, const float* __restrict__ B,
    const float* __restrict__ bias, const int* __restrict__ deg,
    const float* __restrict__ b2, unsigned short* __restrict__ out, int n) {
    constexpr int SK = 136;  // padded K stride (bf16 elems)
    __shared__ unsigned short Bt[NC * SK];
    int tid = threadIdx.x;
    for (int idx = tid; idx < 128 * NC; idx += 256) {
        int k = idx / NC, c = idx % NC;
        Bt[c * SK + k] = f2bf(B[idx]);
    }
    __syncthreads();

    int wave = tid >> 6, lane = tid & 63;
    int quad = lane >> 4, m = lane & 15;
    int rowBase = blockIdx.x * 128 + wave * 32;

    short8 a[2][4];
#pragma unroll
    for (int rt = 0; rt < 2; rt++) {
        int r = rowBase + rt * 16 + m;
        int rc = (r < n) ? r : (n - 1);
        const unsigned short* ap = A + (size_t)rc * 128 + quad * 8;
#pragma unroll
        for (int s = 0; s < 4; s++) a[rt][s] = *(const short8*)(ap + s * 32);
    }

    constexpr int NT = NC / 16;
    floatx4 acc[2][NT];
    floatx4 z = {0.0f, 0.0f, 0.0f, 0.0f};
#pragma unroll
    for (int rt = 0; rt < 2; rt++)
#pragma unroll
        for (int ct = 0; ct < NT; ct++) acc[rt][ct] = z;

#pragma unroll
    for (int ct = 0; ct < NT; ct++) {
        const unsigned short* bp = &Bt[(ct * 16 + m) * SK + quad * 8];
#pragma unroll
        for (int s = 0; s < 4; s++) {
            short8 b = *(const short8*)(bp + s * 32);
            acc[0][ct] = __builtin_amdgcn_mfma_f32_16x16x32_bf16(a[0][s], b, acc[0][ct], 0, 0, 0);
            acc[1][ct] = __builtin_amdgcn_mfma_f32_16x16x32_bf16(a[1][s], b, acc[1][ct], 0, 0, 0);
        }
    }

    float dv[2][4];
    if (EPI == 2) {
#pragma unroll
        for (int rt = 0; rt < 2; rt++)
#pragma unroll
            for (int r = 0; r < 4; r++) {
                int orow = rowBase + rt * 16 + quad * 4 + r;
                dv[rt][r] = (orow < n) ? (float)deg[orow] : 0.0f;
            }
    }

#pragma unroll
    for (int ct = 0; ct < NT; ct++) {
        int col = ct * 16 + m;
        float bv = (EPI == 0) ? 0.0f : ((EPI == 2) ? b2[col] : bias[col]);
#pragma unroll
        for (int rt = 0; rt < 2; rt++) {
#pragma unroll
            for (int r = 0; r < 4; r++) {
                int orow = rowBase + rt * 16 + quad * 4 + r;
                if (orow < n) {
                    float v = acc[rt][ct][r];
                    if (EPI == 1 || EPI == 3) v += bv;
                    if (EPI == 2) v += dv[rt][r] * bv;
                    if (EPI == 3) v = fmaxf(v, 0.0f);
                    out[(size_t)orow * NC + col] = f2bf(v);
                }
            }
        }
    }
}

// ---------------- edge aggregation (CSR): S[i] = sum_e relu(t[src]+ppf@W1p+b1) ----------------

__global__ __launch_bounds__(256, 8) void k_agg(
    const int* __restrict__ starts, const int* __restrict__ ssrc,
    const float4* __restrict__ sppf, const unsigned short* __restrict__ t,
    const float* __restrict__ W1p, const float* __restrict__ b1,
    unsigned short* __restrict__ S, int n) {
    int node = blockIdx.x * 2 + (threadIdx.x >> 7);
    int c = threadIdx.x & 127;
    if (node >= n) return;
    float w0 = W1p[c], w1 = W1p[128 + c], w2 = W1p[256 + c], w3 = W1p[384 + c];
    float bb = b1[c];
    int e0 = starts[node], e1 = starts[node + 1];
    float acc = 0.0f;
    if (e0 < e1) {
        int s0 = ssrc[e0];
        float4 pc = sppf[e0];
        float tv = bf2f(t[(size_t)s0 * HD + c]);
        for (int e = e0 + 1; e < e1; e++) {
            int s1 = ssrc[e];
            float4 pn = sppf[e];
            float tv1 = bf2f(t[(size_t)s1 * HD + c]);
            acc += fmaxf(tv + pc.x * w0 + pc.y * w1 + pc.z * w2 + pc.w * w3 + bb, 0.0f);
            tv = tv1; pc = pn;
        }
        acc += fmaxf(tv + pc.x * w0 + pc.y * w1 + pc.z * w2 + pc.w * w3 + bb, 0.0f);
    }
    S[(size_t)node * HD + c] = f2bf(acc);
}

// ---------------- head: out = v@lin2W + b, atomically segment-summed by batch ----------------

__global__ void k_head2(const unsigned short* __restrict__ v, const float* __restrict__ W,
                        const float* __restrict__ b, const int* __restrict__ batch,
                        float* __restrict__ outg, int n) {
    __shared__ float sW[64 * 16];
    __shared__ float sb[16];
    int tid = threadIdx.x;
    for (int idx = tid; idx < 64 * 16; idx += 256) sW[idx] = W[idx];
    if (tid < 16) sb[tid] = b[tid];
    __syncthreads();
    int r = blockIdx.x * 16 + (tid >> 4);
    int c = tid & 15;
    if (r >= n) return;
    const unsigned short* vr = v + (size_t)r * 64;
    float acc = sb[c];
#pragma unroll
    for (int k = 0; k < 64; k++) acc = fmaf(bf2f(vr[k]), sW[k * 16 + c], acc);
    atomicAdd(&outg[batch[r] * 16 + c], acc);
}

// ---------------- launch ----------------

extern "C" void kernel_launch(void* const* d_in, const int* in_sizes, int n_in,
                              void* d_out, int out_size, void* d_ws, size_t ws_size,
                              hipStream_t stream) {
    (void)in_sizes; (void)n_in; (void)out_size; (void)ws_size;
    const float* x    = (const float*)d_in[0];
    const float* pos  = (const float*)d_in[1];
    const int*   ei   = (const int*)d_in[2];
    const int*   batch= (const int*)d_in[3];
    const float* nW1  = (const float*)d_in[4];
    const float* nb1  = (const float*)d_in[5];
    const float* nW2  = (const float*)d_in[6];
    const float* nb2  = (const float*)d_in[7];
    const float* lW1  = (const float*)d_in[8];
    const float* lb1  = (const float*)d_in[9];
    const float* lW2  = (const float*)d_in[10];
    const float* lb2  = (const float*)d_in[11];
    const float* gW1  = (const float*)d_in[12];
    const float* gb1  = (const float*)d_in[13];
    const float* gW2  = (const float*)d_in[14];
    const float* gb2  = (const float*)d_in[15];
    const float* l1W  = (const float*)d_in[16];
    const float* l1b  = (const float*)d_in[17];
    const float* l2W  = (const float*)d_in[18];
    const float* l2b  = (const float*)d_in[19];
    float* outg = (float*)d_out;

    char* ws = (char*)d_ws;
    size_t off = 0;
    auto alloc = [&](size_t bytes) -> void* {
        void* p = ws + off;
        off = (off + bytes + 255) & ~(size_t)255;
        return p;
    };
    unsigned short* P0 = (unsigned short*)alloc((size_t)NN * HD * 2);
    unsigned short* P1 = (unsigned short*)alloc((size_t)NN * HD * 2);
    float4* sppf = (float4*)alloc((size_t)NE * 16);
    int* ssrc    = (int*)alloc((size_t)NE * 4);
    float* nrm   = (float*)alloc((size_t)NN * 3 * 4);
    int* deg     = (int*)alloc((size_t)NN * 4);
    int* starts  = (int*)alloc((size_t)(NN + 2) * 4);
    int* cursor  = (int*)alloc((size_t)NN * 4);
    int* bsum    = (int*)alloc(1024);

    hipMemsetAsync(deg, 0, (size_t)NN * 4, stream);
    hipMemsetAsync(outg, 0, (size_t)NG * 16 * 4, stream);

    k_normal<<<(NN + 255) / 256, 256, 0, stream>>>(pos, nrm, NN);
    k_hist<<<(NE + 255) / 256, 256, 0, stream>>>(ei, deg, NE);
    int n1 = NN + 1;
    int nb = (n1 + 1023) / 1024;
    k_scan1<<<nb, 1024, 0, stream>>>(deg, starts, bsum, n1);
    k_scan2<<<1, 64, 0, stream>>>(bsum, nb);
    k_scan3<<<(n1 + 255) / 256, 256, 0, stream>>>(starts, bsum, n1);
    hipMemcpyAsync(cursor, starts, (size_t)NN * 4, hipMemcpyDeviceToDevice, stream);
    k_ppf_scatter<<<(NE + 255) / 256, 256, 0, stream>>>(ei, pos, nrm, cursor, ssrc, sppf, NE);

    // node_lin
    k_node_lin1<<<(NN + 15) / 16, 256, 0, stream>>>(x, nW1, nb1, P1, NN);
    const int GB = (NN + 127) / 128;
    k_gemm128<128, 1><<<GB, 256, 0, stream>>>(P1, nW2, nb2, nullptr, nullptr, P0, NN);

    unsigned short* hbuf = P0;
    unsigned short* obuf = P1;
    for (int l = 0; l < NL; l++) {
        const float* W1h = lW1 + (size_t)l * 132 * 128;
        const float* W1p = W1h + 128 * 128;
        const float* b1  = lb1 + l * 128;
        const float* W2  = lW2 + (size_t)l * 128 * 128;
        const float* b2  = lb2 + l * 128;
        const float* GW1 = gW1 + (size_t)l * 128 * 128;
        const float* Gb1 = gb1 + l * 128;
        const float* GW2 = gW2 + (size_t)l * 128 * 128;
        const float* Gb2 = gb2 + l * 128;
        // t = h @ W1h
        k_gemm128<128, 0><<<GB, 256, 0, stream>>>(hbuf, W1h, nullptr, nullptr, nullptr, obuf, NN);
        // S = aggregate(t) -> hbuf
        k_agg<<<NN / 2, 256, 0, stream>>>(starts, ssrc, sppf, obuf, W1p, b1, hbuf, NN);
        // A = S @ W2 + deg*b2 -> obuf
        k_gemm128<128, 2><<<GB, 256, 0, stream>>>(hbuf, W2, nullptr, deg, b2, obuf, NN);
        // B = relu(A @ GW1 + Gb1) -> hbuf
        k_gemm128<128, 3><<<GB, 256, 0, stream>>>(obuf, GW1, Gb1, nullptr, nullptr, hbuf, NN);
        // h = relu(B @ GW2 + Gb2) -> obuf
        k_gemm128<128, 3><<<GB, 256, 0, stream>>>(hbuf, GW2, Gb2, nullptr, nullptr, obuf, NN);
        unsigned short* tmp = hbuf; hbuf = obuf; obuf = tmp;
    }
    // v = relu(h @ lin1W + lin1b)  [N,64]
    k_gemm128<64, 3><<<GB, 256, 0, stream>>>(hbuf, l1W, l1b, nullptr, nullptr, obuf, NN);
    // out = v @ lin2W + lin2b, segment-sum by batch
    k_head2<<<(NN + 15) / 16, 256, 0, stream>>>(obuf, l2W, l2b, batch, outg, NN);
}

// Round 2
// 856.196 us; speedup vs baseline: 1.7900x; 1.7900x over previous
//
#include <hip/hip_runtime.h>

#define NN 100000
#define NE 1600000
#define HD 128
#define NL 3
#define NG 256

typedef __attribute__((ext_vector_type(8))) short short8;
typedef __attribute__((ext_vector_type(4))) float floatx4;

static __device__ __forceinline__ unsigned short f2bf(float f) {
    unsigned int u = __float_as_uint(f);
    u += 0x7fffu + ((u >> 16) & 1u);
    return (unsigned short)(u >> 16);
}
static __device__ __forceinline__ float bf2f(unsigned short h) {
    return __uint_as_float(((unsigned int)h) << 16);
}
static __device__ __forceinline__ float angle3(float ax, float ay, float az,
                                               float bx, float by, float bz) {
    float cx = ay*bz - az*by;
    float cy = az*bx - ax*bz;
    float cz = ax*by - ay*bx;
    float cn = sqrtf(cx*cx + cy*cy + cz*cz);
    float d  = ax*bx + ay*by + az*bz;
    return atan2f(cn, d);
}

// ---------------- preprocessing ----------------

__global__ void k_normal(const float* __restrict__ pos, float* __restrict__ nrm, int n) {
    int i = blockIdx.x * blockDim.x + threadIdx.x;
    if (i >= n) return;
    float x = pos[3*i], y = pos[3*i+1], z = pos[3*i+2];
    float inv = 1.0f / (sqrtf(x*x + y*y + z*z) + 1e-12f);
    nrm[3*i] = x*inv; nrm[3*i+1] = y*inv; nrm[3*i+2] = z*inv;
}

__global__ void k_hist(const int* __restrict__ ei, int* __restrict__ deg, int e) {
    int i = blockIdx.x * blockDim.x + threadIdx.x;
    if (i >= e) return;
    atomicAdd(&deg[ei[NE + i]], 1);
}

__global__ void k_scan1(const int* __restrict__ deg, int* __restrict__ starts,
                        int* __restrict__ bsum, int n) {
    __shared__ int s[1024];
    int i = blockIdx.x * 1024 + threadIdx.x;
    int v = (i < NN) ? deg[i] : 0;
    s[threadIdx.x] = v;
    for (int off = 1; off < 1024; off <<= 1) {
        __syncthreads();
        int t = (threadIdx.x >= off) ? s[threadIdx.x - off] : 0;
        __syncthreads();
        s[threadIdx.x] += t;
    }
    if (i < n) starts[i] = s[threadIdx.x] - v;  // exclusive
    if (threadIdx.x == 1023) bsum[blockIdx.x] = s[1023];
}

__global__ void k_scan2(int* __restrict__ bsum, int nb) {
    if (threadIdx.x == 0 && blockIdx.x == 0) {
        int acc = 0;
        for (int i = 0; i < nb; i++) { int v = bsum[i]; bsum[i] = acc; acc += v; }
    }
}

__global__ void k_scan3(int* __restrict__ starts, const int* __restrict__ bsum, int n) {
    int i = blockIdx.x * blockDim.x + threadIdx.x;
    if (i < n) starts[i] += bsum[i >> 10];
}

// compute ppf per edge and scatter into dst-sorted order (counting sort)
__global__ void k_ppf_scatter(const int* __restrict__ ei, const float* __restrict__ pos,
                              const float* __restrict__ nrm, int* __restrict__ cursor,
                              int* __restrict__ ssrc, float4* __restrict__ sppf, int e) {
    int i = blockIdx.x * blockDim.x + threadIdx.x;
    if (i >= e) return;
    int s = ei[i];        // src (j)
    int d = ei[NE + i];   // dst (i)
    float px = pos[3*s] - pos[3*d];
    float py = pos[3*s+1] - pos[3*d+1];
    float pz = pos[3*s+2] - pos[3*d+2];
    float nix = nrm[3*d], niy = nrm[3*d+1], niz = nrm[3*d+2];
    float njx = nrm[3*s], njy = nrm[3*s+1], njz = nrm[3*s+2];
    float f0 = sqrtf(px*px + py*py + pz*pz);
    float f1 = angle3(nix, niy, niz, px, py, pz);
    float f2 = angle3(njx, njy, njz, px, py, pz);
    float f3 = angle3(nix, niy, niz, njx, njy, njz);
    int p = atomicAdd(&cursor[d], 1);
    ssrc[p] = s;
    sppf[p] = make_float4(f0, f1, f2, f3);
}

// ---------------- node_lin first layer: u = relu(x@W1 + b1), K=16 ----------------

__global__ void k_node_lin1(const float* __restrict__ x, const float* __restrict__ W1,
                            const float* __restrict__ b1, unsigned short* __restrict__ u, int n) {
    __shared__ float sW[16 * HD];
    __shared__ float sb[HD];
    __shared__ float sx[16 * 16];
    int tid = threadIdx.x;
    for (int idx = tid; idx < 16 * HD; idx += 256) sW[idx] = W1[idx];
    if (tid < HD) sb[tid] = b1[tid];
    int r0 = blockIdx.x * 16;
    for (int idx = tid; idx < 16 * 16; idx += 256) {
        int r = r0 + (idx >> 4);
        sx[idx] = (r < n) ? x[r * 16 + (idx & 15)] : 0.0f;
    }
    __syncthreads();
    int col = tid & 127;
    int rsub = tid >> 7;
    float wcol[16];
#pragma unroll
    for (int k = 0; k < 16; k++) wcol[k] = sW[k * HD + col];
    float bb = sb[col];
    for (int rr = rsub; rr < 16; rr += 2) {
        int r = r0 + rr;
        if (r >= n) break;
        float acc = bb;
#pragma unroll
        for (int k = 0; k < 16; k++) acc = fmaf(sx[rr * 16 + k], wcol[k], acc);
        u[r * HD + col] = f2bf(fmaxf(acc, 0.0f));
    }
}

// ---------------- main MFMA GEMM: [n,128] bf16 @ [128,NC] f32 -> [n,NC] bf16 ----------------
// EPI: 0 = none, 1 = +bias, 2 = +deg*b2, 3 = +bias,relu

template <int NC, int EPI>
__global__ __launch_bounds__(256, 2) void k_gemm128(
    const unsigned short* __restrict__ A, const float* __restrict__ B,
    const float* __restrict__ bias, const int* __restrict__ deg,
    const float* __restrict__ b2, unsigned short* __restrict__ out, int n) {
    constexpr int SK = 136;  // padded K stride (bf16 elems)
    __shared__ unsigned short Bt[NC * SK];
    int tid = threadIdx.x;
    for (int idx = tid; idx < 128 * NC; idx += 256) {
        int k = idx / NC, c = idx % NC;
        Bt[c * SK + k] = f2bf(B[idx]);
    }
    __syncthreads();

    int wave = tid >> 6, lane = tid & 63;
    int quad = lane >> 4, m = lane & 15;
    int rowBase = blockIdx.x * 128 + wave * 32;

    short8 a[2][4];
#pragma unroll
    for (int rt = 0; rt < 2; rt++) {
        int r = rowBase + rt * 16 + m;
        int rc = (r < n) ? r : (n - 1);
        const unsigned short* ap = A + (size_t)rc * 128 + quad * 8;
#pragma unroll
        for (int s = 0; s < 4; s++) a[rt][s] = *(const short8*)(ap + s * 32);
    }

    constexpr int NT = NC / 16;
    floatx4 acc[2][NT];
    floatx4 z = {0.0f, 0.0f, 0.0f, 0.0f};
#pragma unroll
    for (int rt = 0; rt < 2; rt++)
#pragma unroll
        for (int ct = 0; ct < NT; ct++) acc[rt][ct] = z;

#pragma unroll
    for (int ct = 0; ct < NT; ct++) {
        const unsigned short* bp = &Bt[(ct * 16 + m) * SK + quad * 8];
#pragma unroll
        for (int s = 0; s < 4; s++) {
            short8 b = *(const short8*)(bp + s * 32);
            acc[0][ct] = __builtin_amdgcn_mfma_f32_16x16x32_bf16(a[0][s], b, acc[0][ct], 0, 0, 0);
            acc[1][ct] = __builtin_amdgcn_mfma_f32_16x16x32_bf16(a[1][s], b, acc[1][ct], 0, 0, 0);
        }
    }

    float dv[2][4];
    if (EPI == 2) {
#pragma unroll
        for (int rt = 0; rt < 2; rt++)
#pragma unroll
            for (int r = 0; r < 4; r++) {
                int orow = rowBase + rt * 16 + quad * 4 + r;
                dv[rt][r] = (orow < n) ? (float)deg[orow] : 0.0f;
            }
    }

#pragma unroll
    for (int ct = 0; ct < NT; ct++) {
        int col = ct * 16 + m;
        float bv = (EPI == 0) ? 0.0f : ((EPI == 2) ? b2[col] : bias[col]);
#pragma unroll
        for (int rt = 0; rt < 2; rt++) {
#pragma unroll
            for (int r = 0; r < 4; r++) {
                int orow = rowBase + rt * 16 + quad * 4 + r;
                if (orow < n) {
                    float v = acc[rt][ct][r];
                    if (EPI == 1 || EPI == 3) v += bv;
                    if (EPI == 2) v += dv[rt][r] * bv;
                    if (EPI == 3) v = fmaxf(v, 0.0f);
                    out[(size_t)orow * NC + col] = f2bf(v);
                }
            }
        }
    }
}

// ---------------- edge aggregation (CSR): S[i] = sum_e relu(t[src]+ppf@W1p+b1) ----------------
// One wave per node; lane owns channels (2*lane, 2*lane+1); t viewed as uint[N][64].
// Edge metadata (ssrc/sppf) is wave-uniform -> scalar loads; t-row gather is a
// single coalesced 256B dword load per edge. Unroll 4 for 4 gathers in flight.

static __device__ __forceinline__ void agg_edge(unsigned int u, float4 p,
                                                float2 w0, float2 w1, float2 w2, float2 w3,
                                                float2 bb, float& a0, float& a1) {
    float tlo = __uint_as_float(u << 16);
    float thi = __uint_as_float(u & 0xffff0000u);
    float g0 = fmaf(p.x, w0.x, fmaf(p.y, w1.x, fmaf(p.z, w2.x, fmaf(p.w, w3.x, bb.x + tlo))));
    float g1 = fmaf(p.x, w0.y, fmaf(p.y, w1.y, fmaf(p.z, w2.y, fmaf(p.w, w3.y, bb.y + thi))));
    a0 += fmaxf(g0, 0.0f);
    a1 += fmaxf(g1, 0.0f);
}

__global__ __launch_bounds__(256, 8) void k_agg(
    const int* __restrict__ starts, const int* __restrict__ ssrc,
    const float4* __restrict__ sppf, const unsigned int* __restrict__ t,
    const float* __restrict__ W1p, const float* __restrict__ b1,
    unsigned int* __restrict__ S, int n) {
    int node = (blockIdx.x * 256 + threadIdx.x) >> 6;
    if (node >= n) return;
    int lane = threadIdx.x & 63;
    int c2 = lane * 2;
    float2 w0 = *(const float2*)(W1p + c2);
    float2 w1 = *(const float2*)(W1p + 128 + c2);
    float2 w2 = *(const float2*)(W1p + 256 + c2);
    float2 w3 = *(const float2*)(W1p + 384 + c2);
    float2 bb = *(const float2*)(b1 + c2);
    int e0 = __builtin_amdgcn_readfirstlane(starts[node]);
    int e1 = __builtin_amdgcn_readfirstlane(starts[node + 1]);
    float a0 = 0.0f, a1 = 0.0f;
    int e = e0;
    for (; e + 4 <= e1; e += 4) {
        int s0 = ssrc[e], s1 = ssrc[e + 1], s2 = ssrc[e + 2], s3 = ssrc[e + 3];
        float4 p0 = sppf[e], p1 = sppf[e + 1], p2 = sppf[e + 2], p3 = sppf[e + 3];
        unsigned int u0 = t[(size_t)s0 * 64 + lane];
        unsigned int u1 = t[(size_t)s1 * 64 + lane];
        unsigned int u2 = t[(size_t)s2 * 64 + lane];
        unsigned int u3 = t[(size_t)s3 * 64 + lane];
        agg_edge(u0, p0, w0, w1, w2, w3, bb, a0, a1);
        agg_edge(u1, p1, w0, w1, w2, w3, bb, a0, a1);
        agg_edge(u2, p2, w0, w1, w2, w3, bb, a0, a1);
        agg_edge(u3, p3, w0, w1, w2, w3, bb, a0, a1);
    }
    for (; e < e1; e++) {
        int s0 = ssrc[e];
        float4 p0 = sppf[e];
        unsigned int u0 = t[(size_t)s0 * 64 + lane];
        agg_edge(u0, p0, w0, w1, w2, w3, bb, a0, a1);
    }
    unsigned int r = ((unsigned int)f2bf(a1) << 16) | f2bf(a0);
    S[(size_t)node * 64 + lane] = r;
}

// ---------------- head: out = v@lin2W + b, atomically segment-summed by batch ----------------

__global__ void k_head2(const unsigned short* __restrict__ v, const float* __restrict__ W,
                        const float* __restrict__ b, const int* __restrict__ batch,
                        float* __restrict__ outg, int n) {
    __shared__ float sW[64 * 16];
    __shared__ float sb[16];
    int tid = threadIdx.x;
    for (int idx = tid; idx < 64 * 16; idx += 256) sW[idx] = W[idx];
    if (tid < 16) sb[tid] = b[tid];
    __syncthreads();
    int r = blockIdx.x * 16 + (tid >> 4);
    int c = tid & 15;
    if (r >= n) return;
    const unsigned short* vr = v + (size_t)r * 64;
    float acc = sb[c];
#pragma unroll
    for (int k = 0; k < 64; k++) acc = fmaf(bf2f(vr[k]), sW[k * 16 + c], acc);
    atomicAdd(&outg[batch[r] * 16 + c], acc);
}

// ---------------- launch ----------------

extern "C" void kernel_launch(void* const* d_in, const int* in_sizes, int n_in,
                              void* d_out, int out_size, void* d_ws, size_t ws_size,
                              hipStream_t stream) {
    (void)in_sizes; (void)n_in; (void)out_size; (void)ws_size;
    const float* x    = (const float*)d_in[0];
    const float* pos  = (const float*)d_in[1];
    const int*   ei   = (const int*)d_in[2];
    const int*   batch= (const int*)d_in[3];
    const float* nW1  = (const float*)d_in[4];
    const float* nb1  = (const float*)d_in[5];
    const float* nW2  = (const float*)d_in[6];
    const float* nb2  = (const float*)d_in[7];
    const float* lW1  = (const float*)d_in[8];
    const float* lb1  = (const float*)d_in[9];
    const float* lW2  = (const float*)d_in[10];
    const float* lb2  = (const float*)d_in[11];
    const float* gW1  = (const float*)d_in[12];
    const float* gb1  = (const float*)d_in[13];
    const float* gW2  = (const float*)d_in[14];
    const float* gb2  = (const float*)d_in[15];
    const float* l1W  = (const float*)d_in[16];
    const float* l1b  = (const float*)d_in[17];
    const float* l2W  = (const float*)d_in[18];
    const float* l2b  = (const float*)d_in[19];
    float* outg = (float*)d_out;

    char* ws = (char*)d_ws;
    size_t off = 0;
    auto alloc = [&](size_t bytes) -> void* {
        void* p = ws + off;
        off = (off + bytes + 255) & ~(size_t)255;
        return p;
    };
    unsigned short* P0 = (unsigned short*)alloc((size_t)NN * HD * 2);
    unsigned short* P1 = (unsigned short*)alloc((size_t)NN * HD * 2);
    float4* sppf = (float4*)alloc((size_t)NE * 16);
    int* ssrc    = (int*)alloc((size_t)NE * 4);
    float* nrm   = (float*)alloc((size_t)NN * 3 * 4);
    int* deg     = (int*)alloc((size_t)NN * 4);
    int* starts  = (int*)alloc((size_t)(NN + 2) * 4);
    int* cursor  = (int*)alloc((size_t)NN * 4);
    int* bsum    = (int*)alloc(1024);

    hipMemsetAsync(deg, 0, (size_t)NN * 4, stream);
    hipMemsetAsync(outg, 0, (size_t)NG * 16 * 4, stream);

    k_normal<<<(NN + 255) / 256, 256, 0, stream>>>(pos, nrm, NN);
    k_hist<<<(NE + 255) / 256, 256, 0, stream>>>(ei, deg, NE);
    int n1 = NN + 1;
    int nb = (n1 + 1023) / 1024;
    k_scan1<<<nb, 1024, 0, stream>>>(deg, starts, bsum, n1);
    k_scan2<<<1, 64, 0, stream>>>(bsum, nb);
    k_scan3<<<(n1 + 255) / 256, 256, 0, stream>>>(starts, bsum, n1);
    hipMemcpyAsync(cursor, starts, (size_t)NN * 4, hipMemcpyDeviceToDevice, stream);
    k_ppf_scatter<<<(NE + 255) / 256, 256, 0, stream>>>(ei, pos, nrm, cursor, ssrc, sppf, NE);

    // node_lin
    k_node_lin1<<<(NN + 15) / 16, 256, 0, stream>>>(x, nW1, nb1, P1, NN);
    const int GB = (NN + 127) / 128;
    k_gemm128<128, 1><<<GB, 256, 0, stream>>>(P1, nW2, nb2, nullptr, nullptr, P0, NN);

    unsigned short* hbuf = P0;
    unsigned short* obuf = P1;
    const int AGB = (NN * 64 + 255) / 256;  // one wave per node, 4 nodes/block
    for (int l = 0; l < NL; l++) {
        const float* W1h = lW1 + (size_t)l * 132 * 128;
        const float* W1p = W1h + 128 * 128;
        const float* b1  = lb1 + l * 128;
        const float* W2  = lW2 + (size_t)l * 128 * 128;
        const float* b2  = lb2 + l * 128;
        const float* GW1 = gW1 + (size_t)l * 128 * 128;
        const float* Gb1 = gb1 + l * 128;
        const float* GW2 = gW2 + (size_t)l * 128 * 128;
        const float* Gb2 = gb2 + l * 128;
        // t = h @ W1h
        k_gemm128<128, 0><<<GB, 256, 0, stream>>>(hbuf, W1h, nullptr, nullptr, nullptr, obuf, NN);
        // S = aggregate(t) -> hbuf
        k_agg<<<AGB, 256, 0, stream>>>(starts, ssrc, sppf, (const unsigned int*)obuf,
                                       W1p, b1, (unsigned int*)hbuf, NN);
        // A = S @ W2 + deg*b2 -> obuf
        k_gemm128<128, 2><<<GB, 256, 0, stream>>>(hbuf, W2, nullptr, deg, b2, obuf, NN);
        // B = relu(A @ GW1 + Gb1) -> hbuf
        k_gemm128<128, 3><<<GB, 256, 0, stream>>>(obuf, GW1, Gb1, nullptr, nullptr, hbuf, NN);
        // h = relu(B @ GW2 + Gb2) -> obuf
        k_gemm128<128, 3><<<GB, 256, 0, stream>>>(hbuf, GW2, Gb2, nullptr, nullptr, obuf, NN);
        unsigned short* tmp = hbuf; hbuf = obuf; obuf = tmp;
    }
    // v = relu(h @ lin1W + lin1b)  [N,64]
    k_gemm128<64, 3><<<GB, 256, 0, stream>>>(hbuf, l1W, l1b, nullptr, nullptr, obuf, NN);
    // out = v @ lin2W + lin2b, segment-sum by batch
    k_head2<<<(NN + 15) / 16, 256, 0, stream>>>(obuf, l2W, l2b, batch, outg, NN);
}